// Round 5
// baseline (177.235 us; speedup 1.0000x reference)
//
#include <hip/hip_runtime.h>
#include <hip/hip_bf16.h>
#include <math.h>

typedef __attribute__((ext_vector_type(8))) __bf16 bf16x8;
typedef __attribute__((ext_vector_type(4))) float f32x4;

#define HEADS 12
#define DHEAD 64
#define NTOK 2049
#define BATCH 2
#define DIM 768
#define QKV3 2304
#define MROWS 4098   // BATCH*NTOK
#define MP 4224      // padded to 33*128
#define ATT_SCALE 0.125f
#define BKS 64
#define NSPLIT 33    // 33 chunks of 64 keys cover 2049
#define PSTRIDE 68   // floats per (b,h,split) partial record: o[64], m, l, pad

#define TQKV_BX 72
#define TQKV_BLOCKS (72 * 24)
#define TOUT_BX 24
#define TOUT_BLOCKS (24 * 24)
#define PREP_BLOCKS (TQKV_BLOCKS + TOUT_BLOCKS)
#define WIN_BLOCKS (BATCH * 129 * 3)   // 774

// ---------------- prep: transpose+convert weights ----------------
__global__ __launch_bounds__(256) void prep_kernel(const float* __restrict__ w_qkv,
                                                   const float* __restrict__ w_out,
                                                   __bf16* __restrict__ wqkvT,
                                                   __bf16* __restrict__ woutT) {
  __shared__ float tile[32][33];
  const int b = blockIdx.x, tid = threadIdx.x;
  const float* in;
  __bf16* outp;
  int C, bx, by;
  if (b < TQKV_BLOCKS) {
    bx = b % TQKV_BX; by = b / TQKV_BX;
    in = w_qkv; outp = wqkvT; C = QKV3;
  } else {
    int idx = b - TQKV_BLOCKS;
    bx = idx % TOUT_BX; by = idx / TOUT_BX;
    in = w_out; outp = woutT; C = DIM;
  }
  const int R = DIM;
  const int c0 = bx * 32, r0 = by * 32;
  const int tx = tid & 31, ty = tid >> 5;
#pragma unroll
  for (int i = 0; i < 4; ++i) {
    int r = ty + i * 8;
    tile[r][tx] = in[(size_t)(r0 + r) * C + c0 + tx];
  }
  __syncthreads();
#pragma unroll
  for (int i = 0; i < 4; ++i) {
    int r = ty + i * 8;
    outp[(size_t)(c0 + r) * R + r0 + tx] = (__bf16)tile[tx][r];
  }
}

// ---------------- qkv GEMM: qkv[M][N] = x[M][768](fp32) * wqkvT[N][768]^T ----------------
// 128x128 tile, 4 waves, BK=64, dbuf. A: reg-staged fp32->bf16 (fuses the convert;
// loads issue BEFORE the MFMA section, ds_write after = T14 split). B: global_load_lds.
// T2 swizzle on both (A via ds_write to linear lane slot of inverse-swizzled source col;
// B via pre-swizzled global source). One __syncthreads per K-iter.
__global__ __launch_bounds__(256) void gemm_qkv_kernel(const float* __restrict__ X,
                                                       const __bf16* __restrict__ Bt,
                                                       __bf16* __restrict__ C) {
  __shared__ __bf16 sA[2][128 * BKS];
  __shared__ __bf16 sB[2][128 * BKS];
  const int tid = threadIdx.x;
  const int w = tid >> 6, lane = tid & 63;
  const int m0 = blockIdx.y * 128, n0 = blockIdx.x * 128;
  const int wr = w >> 1, wc = w & 1;
  f32x4 acc[4][4] = {};

  const int srow = (w << 5) + (lane >> 3);                 // + it*8 (preserves row&7)
  const int scolE = ((lane & 7) ^ (lane >> 3)) << 3;       // inverse-swizzled source col
  const __bf16* gB = Bt + (size_t)(n0 + srow) * DIM + scolE;
  const int ldsoff0 = (w << 2) << 9;

  const int nk = DIM / BKS;  // 12
  float4 av[4][2];

#define LOAD_A(kt)                                                              \
  do {                                                                          \
    _Pragma("unroll")                                                           \
    for (int it = 0; it < 4; ++it) {                                            \
      int row = m0 + srow + it * 8;                                             \
      if (row < MROWS) {                                                        \
        const float* gp = X + (size_t)row * DIM + (kt) + scolE;                 \
        av[it][0] = *(const float4*)gp;                                         \
        av[it][1] = *(const float4*)(gp + 4);                                   \
      } else {                                                                  \
        av[it][0] = make_float4(0.f, 0.f, 0.f, 0.f);                            \
        av[it][1] = make_float4(0.f, 0.f, 0.f, 0.f);                            \
      }                                                                         \
    }                                                                           \
  } while (0)

#define WRITE_A(buf)                                                            \
  do {                                                                          \
    _Pragma("unroll")                                                           \
    for (int it = 0; it < 4; ++it) {                                            \
      bf16x8 v;                                                                 \
      _Pragma("unroll")                                                         \
      for (int j = 0; j < 4; ++j) {                                             \
        v[j] = (__bf16)((&av[it][0].x)[j]);                                     \
        v[4 + j] = (__bf16)((&av[it][1].x)[j]);                                 \
      }                                                                         \
      *(bf16x8*)&sA[buf][ldsoff0 + (it << 9) + lane * 8] = v;                   \
    }                                                                           \
  } while (0)

#define STAGE_B(buf, kt)                                                                 \
  do {                                                                                   \
    _Pragma("unroll")                                                                    \
    for (int it = 0; it < 4; ++it) {                                                     \
      __builtin_amdgcn_global_load_lds(                                                  \
          (const __attribute__((address_space(1))) void*)(gB + (size_t)(it * 8) * DIM + (kt)), \
          (__attribute__((address_space(3))) void*)(&sB[buf][ldsoff0 + (it << 9)]), 16, 0, 0); \
    }                                                                                    \
  } while (0)

  LOAD_A(0);
  STAGE_B(0, 0);
  WRITE_A(0);
  __syncthreads();  // buf0 ready

  const int sw0 = ((lane >> 4) ^ (lane & 7)) << 3;   // kk=0 swizzled slot
  const int sw1 = sw0 ^ 32;                          // kk=32
  const int rofA = (wr * 64 + (lane & 15)) * BKS;
  const int rofB = (wc * 64 + (lane & 15)) * BKS;

  for (int t = 0; t < nk; ++t) {
    const int cur = t & 1, nx = cur ^ 1;
    if (t + 1 < nk) {
      STAGE_B(nx, (t + 1) * BKS);   // issue first: fly under MFMA
      LOAD_A((t + 1) * BKS);
    }
    const __bf16* bufA = sA[cur];
    const __bf16* bufB = sB[cur];
#pragma unroll
    for (int kk = 0; kk < BKS; kk += 32) {
      const int so = (kk == 0) ? sw0 : sw1;
      bf16x8 af[4], bfr[4];
#pragma unroll
      for (int m = 0; m < 4; ++m)
        af[m] = *(const bf16x8*)&bufA[rofA + m * 16 * BKS + so];
#pragma unroll
      for (int n = 0; n < 4; ++n)
        bfr[n] = *(const bf16x8*)&bufB[rofB + n * 16 * BKS + so];
#pragma unroll
      for (int m = 0; m < 4; ++m)
#pragma unroll
        for (int n = 0; n < 4; ++n)
          acc[m][n] = __builtin_amdgcn_mfma_f32_16x16x32_bf16(af[m], bfr[n], acc[m][n], 0, 0, 0);
    }
    if (t + 1 < nk) WRITE_A(nx);
    __syncthreads();
  }
#undef LOAD_A
#undef WRITE_A
#undef STAGE_B

#pragma unroll
  for (int m = 0; m < 4; ++m) {
#pragma unroll
    for (int n = 0; n < 4; ++n) {
      int col = n0 + wc * 64 + n * 16 + (lane & 15);
      int rbase = m0 + wr * 64 + m * 16 + ((lane >> 4) << 2);
#pragma unroll
      for (int r = 0; r < 4; ++r) {
        C[(size_t)(rbase + r) * QKV3 + col] = (__bf16)acc[m][n][r];
      }
    }
  }
}

// ---------------- out GEMM: out[M][N] = attnb[M][768]*woutT[N][768]^T + bias ----------------
__global__ __launch_bounds__(256) void gemm_out_kernel(const __bf16* __restrict__ A,
                                                       const __bf16* __restrict__ Bt,
                                                       float* __restrict__ Cv,
                                                       const float* __restrict__ bias) {
  __shared__ __bf16 sA[2][128 * BKS];
  __shared__ __bf16 sB[2][128 * BKS];
  const int tid = threadIdx.x;
  const int w = tid >> 6, lane = tid & 63;
  const int m0 = blockIdx.y * 128, n0 = blockIdx.x * 128;
  const int wr = w >> 1, wc = w & 1;
  const int K = DIM, N = DIM;
  f32x4 acc[4][4] = {};

  const int srow = (w << 5) + (lane >> 3);
  const int scol = ((lane & 7) ^ (lane >> 3)) << 3;
  const __bf16* gA = A + (size_t)(m0 + srow) * K + scol;
  const __bf16* gB = Bt + (size_t)(n0 + srow) * K + scol;
  const int ldsoff0 = (w << 2) << 9;
  const int nk = K / BKS;

#define STAGE(buf, kt)                                                                   \
  do {                                                                                   \
    _Pragma("unroll")                                                                    \
    for (int it = 0; it < 4; ++it) {                                                     \
      __builtin_amdgcn_global_load_lds(                                                  \
          (const __attribute__((address_space(1))) void*)(gA + (size_t)(it * 8) * K + (kt)), \
          (__attribute__((address_space(3))) void*)(&sA[buf][ldsoff0 + (it << 9)]), 16, 0, 0); \
      __builtin_amdgcn_global_load_lds(                                                  \
          (const __attribute__((address_space(1))) void*)(gB + (size_t)(it * 8) * K + (kt)), \
          (__attribute__((address_space(3))) void*)(&sB[buf][ldsoff0 + (it << 9)]), 16, 0, 0); \
    }                                                                                    \
  } while (0)

  STAGE(0, 0);
  __syncthreads();

  const int sw0 = ((lane >> 4) ^ (lane & 7)) << 3;
  const int sw1 = sw0 ^ 32;
  const int rofA = (wr * 64 + (lane & 15)) * BKS;
  const int rofB = (wc * 64 + (lane & 15)) * BKS;

  for (int t = 0; t < nk; ++t) {
    const int cur = t & 1;
    if (t + 1 < nk) STAGE(cur ^ 1, (t + 1) * BKS);
    const __bf16* bufA = sA[cur];
    const __bf16* bufB = sB[cur];
#pragma unroll
    for (int kk = 0; kk < BKS; kk += 32) {
      const int so = (kk == 0) ? sw0 : sw1;
      bf16x8 af[4], bfr[4];
#pragma unroll
      for (int m = 0; m < 4; ++m)
        af[m] = *(const bf16x8*)&bufA[rofA + m * 16 * BKS + so];
#pragma unroll
      for (int n = 0; n < 4; ++n)
        bfr[n] = *(const bf16x8*)&bufB[rofB + n * 16 * BKS + so];
#pragma unroll
      for (int m = 0; m < 4; ++m)
#pragma unroll
        for (int n = 0; n < 4; ++n)
          acc[m][n] = __builtin_amdgcn_mfma_f32_16x16x32_bf16(af[m], bfr[n], acc[m][n], 0, 0, 0);
    }
    __syncthreads();
  }
#undef STAGE

#pragma unroll
  for (int m = 0; m < 4; ++m) {
#pragma unroll
    for (int n = 0; n < 4; ++n) {
      int col = n0 + wc * 64 + n * 16 + (lane & 15);
      int rbase = m0 + wr * 64 + m * 16 + ((lane >> 4) << 2);
#pragma unroll
      for (int r = 0; r < 4; ++r) {
        int row = rbase + r;
        if (row < MROWS) Cv[(size_t)row * N + col] = acc[m][n][r] + bias[col];
      }
    }
  }
}

// ---------------- fused attention: windows (t>=1) + CLS split-K partials ----------------
__global__ __launch_bounds__(64) void attn_fused_kernel(const __bf16* __restrict__ qkv,
                                                        __bf16* __restrict__ attnb,
                                                        float* __restrict__ part) {
  __shared__ float sp_lds[64];
  const int lane = threadIdx.x;

  if (blockIdx.x < WIN_BLOCKS) {
    int bidx = blockIdx.x;
    int hg = bidx % 3; bidx /= 3;
    int blk = bidx % 129;
    int bb = bidx / 129;
    int h = hg * 4 + (lane >> 4);
    int qi = lane & 15;
    int t0 = (blk == 0) ? 1 : 2 + 16 * (blk - 1);
    int nt = (blk == 0) ? 1 : ((NTOK - t0) < 16 ? (NTOK - t0) : 16);
    bool active = qi < nt;
    int qt = t0 + (active ? qi : nt - 1);
    const size_t base = (size_t)bb * NTOK * QKV3;

    float q[64];
    {
      const __bf16* qp = qkv + base + (size_t)qt * QKV3 + h * DHEAD;
#pragma unroll
      for (int d0 = 0; d0 < 64; d0 += 8) {
        bf16x8 v = *(const bf16x8*)(qp + d0);
#pragma unroll
        for (int j = 0; j < 8; ++j) q[d0 + j] = (float)v[j];
      }
    }

    float s[17];
    float mx = -3.4e38f;
#pragma unroll
    for (int j = 0; j < 17; ++j) {
      int jc = (j - 1) < (nt - 1) ? (j - 1) : (nt - 1);
      int kt = (j == 0) ? 0 : t0 + jc;
      const __bf16* kp = qkv + base + (size_t)kt * QKV3 + DIM + h * DHEAD;
      float dot = 0.f;
#pragma unroll
      for (int d0 = 0; d0 < 64; d0 += 8) {
        bf16x8 v = *(const bf16x8*)(kp + d0);
#pragma unroll
        for (int jj = 0; jj < 8; ++jj) dot = fmaf(q[d0 + jj], (float)v[jj], dot);
      }
      s[j] = (j <= nt) ? dot * ATT_SCALE : -3.4e38f;
      mx = fmaxf(mx, s[j]);
    }
    float sum = 0.f;
#pragma unroll
    for (int j = 0; j < 17; ++j) {
      s[j] = expf(s[j] - mx);
      sum += s[j];
    }
    float inv = 1.f / sum;

    float o[64];
#pragma unroll
    for (int d = 0; d < 64; ++d) o[d] = 0.f;
#pragma unroll
    for (int j = 0; j < 17; ++j) {
      int jc = (j - 1) < (nt - 1) ? (j - 1) : (nt - 1);
      int vt = (j == 0) ? 0 : t0 + jc;
      const __bf16* vp = qkv + base + (size_t)vt * QKV3 + 2 * DIM + h * DHEAD;
      float p = s[j];
#pragma unroll
      for (int d0 = 0; d0 < 64; d0 += 8) {
        bf16x8 v = *(const bf16x8*)(vp + d0);
#pragma unroll
        for (int jj = 0; jj < 8; ++jj) o[d0 + jj] = fmaf(p, (float)v[jj], o[d0 + jj]);
      }
    }

    if (active) {
      __bf16* op = attnb + (size_t)(bb * NTOK + qt) * DIM + h * DHEAD;
#pragma unroll
      for (int d0 = 0; d0 < 64; d0 += 8) {
        bf16x8 v;
#pragma unroll
        for (int j = 0; j < 8; ++j) v[j] = (__bf16)(o[d0 + j] * inv);
        *(bf16x8*)(op + d0) = v;
      }
    }
    return;
  }

  int bid = blockIdx.x - WIN_BLOCKS;
  const int sp = bid % NSPLIT;
  const int bh = bid / NSPLIT;
  const int h = bh % HEADS;
  const int bb = bh / HEADS;
  const size_t base = (size_t)bb * NTOK * QKV3;

  float q[64];
  {
    const __bf16* qp = qkv + base + h * DHEAD;
#pragma unroll
    for (int d0 = 0; d0 < 64; d0 += 8) {
      bf16x8 v = *(const bf16x8*)(qp + d0);
#pragma unroll
      for (int j = 0; j < 8; ++j) q[d0 + j] = (float)v[j];
    }
  }

  const int t = sp * 64 + lane;
  const bool valid = t < NTOK;
  const int tc = valid ? t : NTOK - 1;
  float dot = 0.f;
  {
    const __bf16* kp = qkv + base + (size_t)tc * QKV3 + DIM + h * DHEAD;
#pragma unroll
    for (int d0 = 0; d0 < 64; d0 += 8) {
      bf16x8 v = *(const bf16x8*)(kp + d0);
#pragma unroll
      for (int j = 0; j < 8; ++j) dot = fmaf(q[d0 + j], (float)v[j], dot);
    }
  }
  float s = valid ? dot * ATT_SCALE : -3.4e38f;

  float m = s;
#pragma unroll
  for (int off = 32; off > 0; off >>= 1) m = fmaxf(m, __shfl_xor(m, off, 64));
  float p = valid ? expf(s - m) : 0.f;
  float l = p;
#pragma unroll
  for (int off = 32; off > 0; off >>= 1) l += __shfl_xor(l, off, 64);

  sp_lds[lane] = p;
  __syncthreads();

  const int nt = (NTOK - sp * 64) < 64 ? (NTOK - sp * 64) : 64;
  float o = 0.f;
  const __bf16* vcol = qkv + base + (size_t)(sp * 64) * QKV3 + 2 * DIM + h * DHEAD + lane;
  for (int tt = 0; tt < nt; ++tt) {
    o = fmaf(sp_lds[tt], (float)vcol[(size_t)tt * QKV3], o);
  }

  float* pb = part + ((size_t)bh * NSPLIT + sp) * PSTRIDE;
  pb[lane] = o;
  if (lane == 0) { pb[64] = m; pb[65] = l; }
}

__global__ __launch_bounds__(64) void attn_cls_reduce(const float* __restrict__ part,
                                                      __bf16* __restrict__ attnb) {
  const int bh = blockIdx.x;
  const int h = bh % HEADS;
  const int bb = bh / HEADS;
  const int lane = threadIdx.x;
  const float* pb0 = part + (size_t)bh * NSPLIT * PSTRIDE;
  float M = -3.4e38f;
#pragma unroll
  for (int i = 0; i < NSPLIT; ++i) M = fmaxf(M, pb0[i * PSTRIDE + 64]);
  float L = 0.f, o = 0.f;
#pragma unroll
  for (int i = 0; i < NSPLIT; ++i) {
    float w = expf(pb0[i * PSTRIDE + 64] - M);
    L = fmaf(pb0[i * PSTRIDE + 65], w, L);
    o = fmaf(pb0[i * PSTRIDE + lane], w, o);
  }
  attnb[(size_t)(bb * NTOK) * DIM + h * DHEAD + lane] = (__bf16)(o / L);
}

// ---------------- launch ----------------
extern "C" void kernel_launch(void* const* d_in, const int* in_sizes, int n_in,
                              void* d_out, int out_size, void* d_ws, size_t ws_size,
                              hipStream_t stream) {
  const float* x = (const float*)d_in[0];
  const float* w_qkv = (const float*)d_in[1];
  const float* w_out = (const float*)d_in[2];
  const float* b_out = (const float*)d_in[3];
  float* out = (float*)d_out;

  char* ws = (char*)d_ws;
  __bf16* wqkvT = (__bf16*)(ws);                                   // QKV3*DIM    (3.54 MB)
  __bf16* woutT = (__bf16*)(ws + 3538944);                         // DIM*DIM     (1.18 MB)
  __bf16* qkvb  = (__bf16*)(ws + 3538944 + 1179648);               // MP*QKV3     (19.5 MB)
  __bf16* attnb = (__bf16*)(ws + 3538944 + 1179648 + 19464192);    // MP*DIM      (6.49 MB)
  float*  clsp  = (float*)(ws + 3538944 + 1179648 + 19464192 + 6488064); // 24*33*68*4 B

  prep_kernel<<<PREP_BLOCKS, 256, 0, stream>>>(w_qkv, w_out, wqkvT, woutT);

  gemm_qkv_kernel<<<dim3(QKV3 / 128, MP / 128), 256, 0, stream>>>(x, wqkvT, qkvb);

  attn_fused_kernel<<<WIN_BLOCKS + BATCH * HEADS * NSPLIT, 64, 0, stream>>>(qkvb, attnb, clsp);
  attn_cls_reduce<<<BATCH * HEADS, 64, 0, stream>>>(clsp, attnb);

  gemm_out_kernel<<<dim3(DIM / 128, MP / 128), 256, 0, stream>>>(attnb, woutT, out, b_out);
}

// Round 6
// 148.612 us; speedup vs baseline: 1.1926x; 1.1926x over previous
//
#include <hip/hip_runtime.h>
#include <hip/hip_bf16.h>
#include <math.h>

typedef __attribute__((ext_vector_type(8))) __bf16 bf16x8;
typedef __attribute__((ext_vector_type(4))) float f32x4;

#define HEADS 12
#define DHEAD 64
#define NTOK 2049
#define BATCH 2
#define DIM 768
#define QKV3 2304
#define MROWS 4098   // BATCH*NTOK
#define MP 4224      // padded to 33*128 (and 66*64)
#define ATT_SCALE 0.125f
#define BKS 64
#define NSPLIT 33    // 33 chunks of 64 keys cover 2049
#define PSTRIDE 68   // floats per (b,h,split) partial record: o[64], m, l, pad

#define CVT_BLOCKS 1584
#define TQKV_BX 72
#define TQKV_BLOCKS (72 * 24)
#define TOUT_BX 24
#define TOUT_BLOCKS (24 * 24)
#define PREP_BLOCKS (CVT_BLOCKS + TQKV_BLOCKS + TOUT_BLOCKS)
#define WIN_BLOCKS (BATCH * 129 * 3)   // 774

// ---------------- fused prep: cvt_x + transpose w_qkv + transpose w_out ----------------
__global__ __launch_bounds__(256) void prep_kernel(const float* __restrict__ x,
                                                   const float* __restrict__ w_qkv,
                                                   const float* __restrict__ w_out,
                                                   __bf16* __restrict__ xb,
                                                   __bf16* __restrict__ wqkvT,
                                                   __bf16* __restrict__ woutT) {
  __shared__ float tile[32][33];
  const int b = blockIdx.x, tid = threadIdx.x;
  if (b < CVT_BLOCKS) {
    long e = ((long)b * 256 + tid) * 8;   // 8 elems/thread, 768%8==0 keeps in-row
    int row = (int)(e / DIM);
    bf16x8 v;
    if (row < MROWS) {
      const float4 a = *(const float4*)(x + e);
      const float4 c = *(const float4*)(x + e + 4);
      v[0] = (__bf16)a.x; v[1] = (__bf16)a.y; v[2] = (__bf16)a.z; v[3] = (__bf16)a.w;
      v[4] = (__bf16)c.x; v[5] = (__bf16)c.y; v[6] = (__bf16)c.z; v[7] = (__bf16)c.w;
    } else {
#pragma unroll
      for (int j = 0; j < 8; ++j) v[j] = (__bf16)0.f;
    }
    *(bf16x8*)(xb + e) = v;
    return;
  }
  const float* in;
  __bf16* outp;
  int C, bx, by;
  if (b < CVT_BLOCKS + TQKV_BLOCKS) {
    int idx = b - CVT_BLOCKS;
    bx = idx % TQKV_BX; by = idx / TQKV_BX;
    in = w_qkv; outp = wqkvT; C = QKV3;
  } else {
    int idx = b - CVT_BLOCKS - TQKV_BLOCKS;
    bx = idx % TOUT_BX; by = idx / TOUT_BX;
    in = w_out; outp = woutT; C = DIM;
  }
  const int R = DIM;
  const int c0 = bx * 32, r0 = by * 32;
  const int tx = tid & 31, ty = tid >> 5;
#pragma unroll
  for (int i = 0; i < 4; ++i) {
    int r = ty + i * 8;
    tile[r][tx] = in[(size_t)(r0 + r) * C + c0 + tx];
  }
  __syncthreads();
#pragma unroll
  for (int i = 0; i < 4; ++i) {
    int r = ty + i * 8;
    outp[(size_t)(c0 + r) * R + r0 + tx] = (__bf16)tile[tx][r];
  }
}

// ---------------- qkv GEMM: C[M][2304] = xb[M][768] * wqkvT[2304][768]^T ----------------
// 64x128 tile (1188 blocks for grid occupancy), 4 waves 2x2 (each 32x64), BK=64,
// dbuf + prefetch-first, T2 swizzle via inverse-swizzled global source col.
__global__ __launch_bounds__(256) void gemm_qkv_kernel(const __bf16* __restrict__ A,
                                                       const __bf16* __restrict__ Bt,
                                                       __bf16* __restrict__ C) {
  __shared__ __bf16 sA[2][64 * BKS];
  __shared__ __bf16 sB[2][128 * BKS];
  const int tid = threadIdx.x;
  const int w = tid >> 6, lane = tid & 63;
  const int m0 = blockIdx.y * 64, n0 = blockIdx.x * 128;
  const int wr = w >> 1, wc = w & 1;
  const int K = DIM;
  f32x4 acc[2][4] = {};

  const int srow = (w << 3) + (lane >> 3);                 // 0..31; +it*32 keeps row&7
  const int scolE = ((lane & 7) ^ (lane >> 3)) << 3;       // inverse-swizzled source col
  const __bf16* gA = A + (size_t)(m0 + srow) * K + scolE;
  const __bf16* gB = Bt + (size_t)(n0 + srow) * K + scolE;
  const int nk = K / BKS;  // 12

#define STAGE_Q(buf, kt)                                                                 \
  do {                                                                                   \
    _Pragma("unroll")                                                                    \
    for (int it = 0; it < 2; ++it) {                                                     \
      __builtin_amdgcn_global_load_lds(                                                  \
          (const __attribute__((address_space(1))) void*)(gA + (size_t)(it * 32) * K + (kt)), \
          (__attribute__((address_space(3))) void*)(&sA[buf][(it << 11) + (w << 9)]), 16, 0, 0); \
    }                                                                                    \
    _Pragma("unroll")                                                                    \
    for (int it = 0; it < 4; ++it) {                                                     \
      __builtin_amdgcn_global_load_lds(                                                  \
          (const __attribute__((address_space(1))) void*)(gB + (size_t)(it * 32) * K + (kt)), \
          (__attribute__((address_space(3))) void*)(&sB[buf][(it << 11) + (w << 9)]), 16, 0, 0); \
    }                                                                                    \
  } while (0)

  STAGE_Q(0, 0);
  __syncthreads();

  const int sw0 = ((lane >> 4) ^ (lane & 7)) << 3;   // kk=0 swizzled slot
  const int sw1 = sw0 ^ 32;                          // kk=32
  const int rofA = (wr * 32 + (lane & 15)) * BKS;
  const int rofB = (wc * 64 + (lane & 15)) * BKS;

  for (int t = 0; t < nk; ++t) {
    const int cur = t & 1;
    if (t + 1 < nk) STAGE_Q(cur ^ 1, (t + 1) * BKS);  // issue next-tile loads first
    const __bf16* bufA = sA[cur];
    const __bf16* bufB = sB[cur];
#pragma unroll
    for (int kk = 0; kk < BKS; kk += 32) {
      const int so = (kk == 0) ? sw0 : sw1;
      bf16x8 af[2], bfr[4];
#pragma unroll
      for (int m = 0; m < 2; ++m)
        af[m] = *(const bf16x8*)&bufA[rofA + m * 16 * BKS + so];
#pragma unroll
      for (int n = 0; n < 4; ++n)
        bfr[n] = *(const bf16x8*)&bufB[rofB + n * 16 * BKS + so];
#pragma unroll
      for (int m = 0; m < 2; ++m)
#pragma unroll
        for (int n = 0; n < 4; ++n)
          acc[m][n] = __builtin_amdgcn_mfma_f32_16x16x32_bf16(af[m], bfr[n], acc[m][n], 0, 0, 0);
    }
    __syncthreads();
  }
#undef STAGE_Q

#pragma unroll
  for (int m = 0; m < 2; ++m) {
#pragma unroll
    for (int n = 0; n < 4; ++n) {
      int col = n0 + wc * 64 + n * 16 + (lane & 15);
      int rbase = m0 + wr * 32 + m * 16 + ((lane >> 4) << 2);
#pragma unroll
      for (int r = 0; r < 4; ++r) {
        C[(size_t)(rbase + r) * QKV3 + col] = (__bf16)acc[m][n][r];
      }
    }
  }
}

// ---------------- out GEMM: out[M][768] = attnb[M][768]*woutT[768][768]^T + bias ----------------
// 64x64 tile (792 blocks), 4 waves 2x2 (each 32x32), BK=64, dbuf, swizzle.
__global__ __launch_bounds__(256) void gemm_out_kernel(const __bf16* __restrict__ A,
                                                       const __bf16* __restrict__ Bt,
                                                       float* __restrict__ Cv,
                                                       const float* __restrict__ bias) {
  __shared__ __bf16 sA[2][64 * BKS];
  __shared__ __bf16 sB[2][64 * BKS];
  const int tid = threadIdx.x;
  const int w = tid >> 6, lane = tid & 63;
  const int m0 = blockIdx.y * 64, n0 = blockIdx.x * 64;
  const int wr = w >> 1, wc = w & 1;
  const int K = DIM, N = DIM;
  f32x4 acc[2][2] = {};

  const int srow = (w << 3) + (lane >> 3);
  const int scol = ((lane & 7) ^ (lane >> 3)) << 3;
  const __bf16* gA = A + (size_t)(m0 + srow) * K + scol;
  const __bf16* gB = Bt + (size_t)(n0 + srow) * K + scol;
  const int nk = K / BKS;

#define STAGE_O(buf, kt)                                                                 \
  do {                                                                                   \
    _Pragma("unroll")                                                                    \
    for (int it = 0; it < 2; ++it) {                                                     \
      __builtin_amdgcn_global_load_lds(                                                  \
          (const __attribute__((address_space(1))) void*)(gA + (size_t)(it * 32) * K + (kt)), \
          (__attribute__((address_space(3))) void*)(&sA[buf][(it << 11) + (w << 9)]), 16, 0, 0); \
      __builtin_amdgcn_global_load_lds(                                                  \
          (const __attribute__((address_space(1))) void*)(gB + (size_t)(it * 32) * K + (kt)), \
          (__attribute__((address_space(3))) void*)(&sB[buf][(it << 11) + (w << 9)]), 16, 0, 0); \
    }                                                                                    \
  } while (0)

  STAGE_O(0, 0);
  __syncthreads();

  const int sw0 = ((lane >> 4) ^ (lane & 7)) << 3;
  const int sw1 = sw0 ^ 32;
  const int rofA = (wr * 32 + (lane & 15)) * BKS;
  const int rofB = (wc * 32 + (lane & 15)) * BKS;

  for (int t = 0; t < nk; ++t) {
    const int cur = t & 1;
    if (t + 1 < nk) STAGE_O(cur ^ 1, (t + 1) * BKS);
    const __bf16* bufA = sA[cur];
    const __bf16* bufB = sB[cur];
#pragma unroll
    for (int kk = 0; kk < BKS; kk += 32) {
      const int so = (kk == 0) ? sw0 : sw1;
      bf16x8 af[2], bfr[2];
#pragma unroll
      for (int m = 0; m < 2; ++m)
        af[m] = *(const bf16x8*)&bufA[rofA + m * 16 * BKS + so];
#pragma unroll
      for (int n = 0; n < 2; ++n)
        bfr[n] = *(const bf16x8*)&bufB[rofB + n * 16 * BKS + so];
#pragma unroll
      for (int m = 0; m < 2; ++m)
#pragma unroll
        for (int n = 0; n < 2; ++n)
          acc[m][n] = __builtin_amdgcn_mfma_f32_16x16x32_bf16(af[m], bfr[n], acc[m][n], 0, 0, 0);
    }
    __syncthreads();
  }
#undef STAGE_O

#pragma unroll
  for (int m = 0; m < 2; ++m) {
#pragma unroll
    for (int n = 0; n < 2; ++n) {
      int col = n0 + wc * 32 + n * 16 + (lane & 15);
      int rbase = m0 + wr * 32 + m * 16 + ((lane >> 4) << 2);
#pragma unroll
      for (int r = 0; r < 4; ++r) {
        int row = rbase + r;
        if (row < MROWS) Cv[(size_t)row * N + col] = acc[m][n][r] + bias[col];
      }
    }
  }
}

// ---------------- fused attention: windows (t>=1) + CLS split-K partials ----------------
__global__ __launch_bounds__(64) void attn_fused_kernel(const __bf16* __restrict__ qkv,
                                                        __bf16* __restrict__ attnb,
                                                        float* __restrict__ part) {
  __shared__ float sp_lds[64];
  const int lane = threadIdx.x;

  if (blockIdx.x < WIN_BLOCKS) {
    int bidx = blockIdx.x;
    int hg = bidx % 3; bidx /= 3;
    int blk = bidx % 129;
    int bb = bidx / 129;
    int h = hg * 4 + (lane >> 4);
    int qi = lane & 15;
    int t0 = (blk == 0) ? 1 : 2 + 16 * (blk - 1);
    int nt = (blk == 0) ? 1 : ((NTOK - t0) < 16 ? (NTOK - t0) : 16);
    bool active = qi < nt;
    int qt = t0 + (active ? qi : nt - 1);
    const size_t base = (size_t)bb * NTOK * QKV3;

    float q[64];
    {
      const __bf16* qp = qkv + base + (size_t)qt * QKV3 + h * DHEAD;
#pragma unroll
      for (int d0 = 0; d0 < 64; d0 += 8) {
        bf16x8 v = *(const bf16x8*)(qp + d0);
#pragma unroll
        for (int j = 0; j < 8; ++j) q[d0 + j] = (float)v[j];
      }
    }

    float s[17];
    float mx = -3.4e38f;
#pragma unroll
    for (int j = 0; j < 17; ++j) {
      int jc = (j - 1) < (nt - 1) ? (j - 1) : (nt - 1);
      int kt = (j == 0) ? 0 : t0 + jc;
      const __bf16* kp = qkv + base + (size_t)kt * QKV3 + DIM + h * DHEAD;
      float dot = 0.f;
#pragma unroll
      for (int d0 = 0; d0 < 64; d0 += 8) {
        bf16x8 v = *(const bf16x8*)(kp + d0);
#pragma unroll
        for (int jj = 0; jj < 8; ++jj) dot = fmaf(q[d0 + jj], (float)v[jj], dot);
      }
      s[j] = (j <= nt) ? dot * ATT_SCALE : -3.4e38f;
      mx = fmaxf(mx, s[j]);
    }
    float sum = 0.f;
#pragma unroll
    for (int j = 0; j < 17; ++j) {
      s[j] = expf(s[j] - mx);
      sum += s[j];
    }
    float inv = 1.f / sum;

    float o[64];
#pragma unroll
    for (int d = 0; d < 64; ++d) o[d] = 0.f;
#pragma unroll
    for (int j = 0; j < 17; ++j) {
      int jc = (j - 1) < (nt - 1) ? (j - 1) : (nt - 1);
      int vt = (j == 0) ? 0 : t0 + jc;
      const __bf16* vp = qkv + base + (size_t)vt * QKV3 + 2 * DIM + h * DHEAD;
      float p = s[j];
#pragma unroll
      for (int d0 = 0; d0 < 64; d0 += 8) {
        bf16x8 v = *(const bf16x8*)(vp + d0);
#pragma unroll
        for (int jj = 0; jj < 8; ++jj) o[d0 + jj] = fmaf(p, (float)v[jj], o[d0 + jj]);
      }
    }

    if (active) {
      __bf16* op = attnb + (size_t)(bb * NTOK + qt) * DIM + h * DHEAD;
#pragma unroll
      for (int d0 = 0; d0 < 64; d0 += 8) {
        bf16x8 v;
#pragma unroll
        for (int j = 0; j < 8; ++j) v[j] = (__bf16)(o[d0 + j] * inv);
        *(bf16x8*)(op + d0) = v;
      }
    }
    return;
  }

  int bid = blockIdx.x - WIN_BLOCKS;
  const int sp = bid % NSPLIT;
  const int bh = bid / NSPLIT;
  const int h = bh % HEADS;
  const int bb = bh / HEADS;
  const size_t base = (size_t)bb * NTOK * QKV3;

  float q[64];
  {
    const __bf16* qp = qkv + base + h * DHEAD;
#pragma unroll
    for (int d0 = 0; d0 < 64; d0 += 8) {
      bf16x8 v = *(const bf16x8*)(qp + d0);
#pragma unroll
      for (int j = 0; j < 8; ++j) q[d0 + j] = (float)v[j];
    }
  }

  const int t = sp * 64 + lane;
  const bool valid = t < NTOK;
  const int tc = valid ? t : NTOK - 1;
  float dot = 0.f;
  {
    const __bf16* kp = qkv + base + (size_t)tc * QKV3 + DIM + h * DHEAD;
#pragma unroll
    for (int d0 = 0; d0 < 64; d0 += 8) {
      bf16x8 v = *(const bf16x8*)(kp + d0);
#pragma unroll
      for (int j = 0; j < 8; ++j) dot = fmaf(q[d0 + j], (float)v[j], dot);
    }
  }
  float s = valid ? dot * ATT_SCALE : -3.4e38f;

  float m = s;
#pragma unroll
  for (int off = 32; off > 0; off >>= 1) m = fmaxf(m, __shfl_xor(m, off, 64));
  float p = valid ? expf(s - m) : 0.f;
  float l = p;
#pragma unroll
  for (int off = 32; off > 0; off >>= 1) l += __shfl_xor(l, off, 64);

  sp_lds[lane] = p;
  __syncthreads();

  const int nt = (NTOK - sp * 64) < 64 ? (NTOK - sp * 64) : 64;
  float o = 0.f;
  const __bf16* vcol = qkv + base + (size_t)(sp * 64) * QKV3 + 2 * DIM + h * DHEAD + lane;
  for (int tt = 0; tt < nt; ++tt) {
    o = fmaf(sp_lds[tt], (float)vcol[(size_t)tt * QKV3], o);
  }

  float* pb = part + ((size_t)bh * NSPLIT + sp) * PSTRIDE;
  pb[lane] = o;
  if (lane == 0) { pb[64] = m; pb[65] = l; }
}

__global__ __launch_bounds__(64) void attn_cls_reduce(const float* __restrict__ part,
                                                      __bf16* __restrict__ attnb) {
  const int bh = blockIdx.x;
  const int h = bh % HEADS;
  const int bb = bh / HEADS;
  const int lane = threadIdx.x;
  const float* pb0 = part + (size_t)bh * NSPLIT * PSTRIDE;
  float M = -3.4e38f;
#pragma unroll
  for (int i = 0; i < NSPLIT; ++i) M = fmaxf(M, pb0[i * PSTRIDE + 64]);
  float L = 0.f, o = 0.f;
#pragma unroll
  for (int i = 0; i < NSPLIT; ++i) {
    float w = expf(pb0[i * PSTRIDE + 64] - M);
    L = fmaf(pb0[i * PSTRIDE + 65], w, L);
    o = fmaf(pb0[i * PSTRIDE + lane], w, o);
  }
  attnb[(size_t)(bb * NTOK) * DIM + h * DHEAD + lane] = (__bf16)(o / L);
}

// ---------------- launch ----------------
extern "C" void kernel_launch(void* const* d_in, const int* in_sizes, int n_in,
                              void* d_out, int out_size, void* d_ws, size_t ws_size,
                              hipStream_t stream) {
  const float* x = (const float*)d_in[0];
  const float* w_qkv = (const float*)d_in[1];
  const float* w_out = (const float*)d_in[2];
  const float* b_out = (const float*)d_in[3];
  float* out = (float*)d_out;

  char* ws = (char*)d_ws;
  __bf16* xb    = (__bf16*)(ws);                                   // MP*DIM      (6.49 MB)
  __bf16* wqkvT = (__bf16*)(ws + 6488064);                         // QKV3*DIM    (3.54 MB)
  __bf16* woutT = (__bf16*)(ws + 6488064 + 3538944);               // DIM*DIM     (1.18 MB)
  __bf16* qkvb  = (__bf16*)(ws + 6488064 + 3538944 + 1179648);     // MP*QKV3     (19.5 MB)
  __bf16* attnb = (__bf16*)(ws + 6488064 + 3538944 + 1179648 + 19464192); // MP*DIM (6.49 MB)
  float*  clsp  = (float*)(ws + 6488064 + 3538944 + 1179648 + 19464192 + 6488064); // 24*33*68*4 B

  prep_kernel<<<PREP_BLOCKS, 256, 0, stream>>>(x, w_qkv, w_out, xb, wqkvT, woutT);

  gemm_qkv_kernel<<<dim3(QKV3 / 128, MP / 64), 256, 0, stream>>>(xb, wqkvT, qkvb);

  attn_fused_kernel<<<WIN_BLOCKS + BATCH * HEADS * NSPLIT, 64, 0, stream>>>(qkvb, attnb, clsp);
  attn_cls_reduce<<<BATCH * HEADS, 64, 0, stream>>>(clsp, attnb);

  gemm_out_kernel<<<dim3(DIM / 64, MP / 64), 256, 0, stream>>>(attnb, woutT, out, b_out);
}